// Round 10
// baseline (179.572 us; speedup 1.0000x reference)
//
#include <hip/hip_runtime.h>
#include <hip/hip_bf16.h>

typedef __bf16 bf16_t;
typedef __bf16 bf16x4 __attribute__((ext_vector_type(4)));
typedef __bf16 bf16x8 __attribute__((ext_vector_type(8)));
typedef float floatx4 __attribute__((ext_vector_type(4)));
typedef unsigned long long u64;

#define N_NODES 4096
#define F_IN 128
#define NUM_HEADS 4
#define D_HID 64
#define F_OUT 256  // NUM_HEADS * D_HID
#define NEG_SLOPE 0.2f

// ---------------------------------------------------------------------------
// Kernel 0: adjacency -> bitmask. mask[i][c] bit l = (adj[i][c*64+l] >= 0.5).
// 1024 blocks x 256 thr; wave w handles row w; coalesced 256 B/instr loads.
// ---------------------------------------------------------------------------
__global__ __launch_bounds__(256) void mask_kernel(
    const float* __restrict__ adj, u64* __restrict__ mask)
{
    const int w    = blockIdx.x * 4 + (threadIdx.x >> 6);  // row 0..4095
    const int lane = threadIdx.x & 63;
    const float* row = adj + (size_t)w * N_NODES + lane;
    u64* mrow = mask + (size_t)w * 64;
#pragma unroll 4
    for (int c = 0; c < 64; ++c) {
        const float v = row[c * 64];
        const u64 b = __ballot(v >= 0.5f);
        if (lane == 0) mrow[c] = b;
    }
}

// ---------------------------------------------------------------------------
// Kernel 1: projections (f32 in; GB bf16 fragment-linear; el/E1r/E2r f32).
//   GB: g[j][h*64+f] stored so a 16x16x32 MFMA B-fragment is contiguous 1 KB:
//   GB[h][j>>5][f>>4][lane=(f&15)+16*((j>>3)&3)][j&7].
//   el[h][j]  = <ga[j,h,:], w_attn[:32]>
//   E1r[h][j] = exp(<ga[j,h,:], w_attn[32:]>),  E2r[h][j] = exp(0.2*<...>)
// ---------------------------------------------------------------------------
__global__ __launch_bounds__(384) void proj_kernel(
    const float* __restrict__ hmat, const float* __restrict__ Wp,
    const float* __restrict__ Wa, const float* __restrict__ wattn,
    bf16_t* __restrict__ GB, float* __restrict__ el,
    float* __restrict__ E1r, float* __restrict__ E2r)
{
    __shared__ float hl[4][F_IN];
    const int t = threadIdx.x;
    const int j0 = blockIdx.x * 4;

    if (t < 128) {
        const int jl = t >> 5, m0 = (t & 31) * 4;
        *reinterpret_cast<float4*>(&hl[jl][m0]) =
            *reinterpret_cast<const float4*>(&hmat[(size_t)(j0 + jl) * F_IN + m0]);
    }
    __syncthreads();

    float acc[4] = {0.f, 0.f, 0.f, 0.f};

    const float* wptr;
    int stride;
    if (t < 256) { wptr = Wp + t;         stride = 256; }
    else         { wptr = Wa + (t - 256); stride = 128; }

    for (int m = 0; m < F_IN; m += 4) {
        const float w0 = wptr[(size_t)(m + 0) * stride];
        const float w1 = wptr[(size_t)(m + 1) * stride];
        const float w2 = wptr[(size_t)(m + 2) * stride];
        const float w3 = wptr[(size_t)(m + 3) * stride];
#pragma unroll
        for (int jl = 0; jl < 4; ++jl) {
            const float4 hv = *reinterpret_cast<const float4*>(&hl[jl][m]);
            acc[jl] = fmaf(hv.w, w3, fmaf(hv.z, w2, fmaf(hv.y, w1, fmaf(hv.x, w0, acc[jl]))));
        }
    }

    if (t < 256) {
        const int h = t >> 6, f = t & 63;
        bf16x4 o;
#pragma unroll
        for (int q = 0; q < 4; ++q) o[q] = (bf16_t)acc[q];
        const size_t base = ((((size_t)h * 128 + (j0 >> 5)) * 4 + (f >> 4)) * 64
                             + (f & 15) + 16 * ((j0 >> 3) & 3)) * 8 + (j0 & 7);
        *reinterpret_cast<bf16x4*>(&GB[base]) = o;
    } else {
        const int ta = t - 256;
        const int ha = ta >> 5, k = ta & 31;
        const float wl = wattn[k], wr = wattn[32 + k];
#pragma unroll
        for (int jl = 0; jl < 4; ++jl) {
            float vl = acc[jl] * wl;
            float vr = acc[jl] * wr;
#pragma unroll
            for (int s = 16; s >= 1; s >>= 1) {
                vl += __shfl_xor(vl, s, 64);
                vr += __shfl_xor(vr, s, 64);
            }
            if (k == 0) {
                el[ha * N_NODES + j0 + jl]  = vl;
                E1r[ha * N_NODES + j0 + jl] = __expf(vr);
                E2r[ha * N_NODES + j0 + jl] = __expf(NEG_SLOPE * vr);
            }
        }
    }
}

// ---------------------------------------------------------------------------
// Kernel 2: barrier-free fused attention, bitmask A-side, 32-row i-tiles.
// Grid (128 i-tiles, 2 j-chunks) x 1024 thr = 16 waves; wave = (head hh,
// j-interleave js). Wave owns 2 A-frags (rows m, m+16) and sweeps tiles
// kk = jc*32 + js + 4t. A-side per tile = ONE u64 mask load per row (quad-
// broadcast) + coalesced E1r/E2r f32; B-frags = contiguous 1 KB loads from
// fragment-linear GB (L2-resident). Den via all-ones-B MFMA. NO barriers in
// the hot loop; js-partials combined at the end via 3-round LDS (40 KB).
// ---------------------------------------------------------------------------
__global__ __launch_bounds__(1024, 4) void attn_kernel(
    const u64* __restrict__ mask, const bf16_t* __restrict__ GB,
    const float* __restrict__ el, const float* __restrict__ E1r,
    const float* __restrict__ E2r,
    float* __restrict__ num, float* __restrict__ den_g)
{
    __shared__ float lbuf[NUM_HEADS * 2 * 20 * 64];   // 40960 B

    const int tid  = threadIdx.x;
    const int i0   = blockIdx.x * 32;
    const int jc   = blockIdx.y;
    const int wave = tid >> 6;
    const int hh   = wave & 3;            // head
    const int js   = wave >> 2;           // j-interleave slot 0..3
    const int lane = tid & 63;
    const int m    = lane & 15;
    const int quad = lane >> 4;

    const int row0 = i0 + m, row1 = row0 + 16;
    const float el0 = el[hh * N_NODES + row0];
    const float el1 = el[hh * N_NODES + row1];
    const float E1i0 = __expf(el0), E2i0 = __expf(NEG_SLOPE * el0), Ti0 = __expf(-el0);
    const float E1i1 = __expf(el1), E2i1 = __expf(NEG_SLOPE * el1), Ti1 = __expf(-el1);

    const u64* mrow0 = mask + (size_t)row0 * 64;
    const u64* mrow1 = mask + (size_t)row1 * 64;
    const float* E1p = E1r + hh * N_NODES + quad * 8;
    const float* E2p = E2r + hh * N_NODES + quad * 8;
    const bf16_t* gb0 = GB + (size_t)hh * 128 * 2048 + lane * 8;

    floatx4 a00 = {0.f, 0.f, 0.f, 0.f};
    floatx4 a01 = a00, a02 = a00, a03 = a00, ad0 = a00;
    floatx4 a10 = a00, a11 = a00, a12 = a00, a13 = a00, ad1 = a00;
    bf16x8 ones;
#pragma unroll
    for (int q = 0; q < 8; ++q) ones[q] = (bf16_t)1.0f;

#pragma unroll 2
    for (int t = 0; t < 8; ++t) {
        const int kk = jc * 32 + js + t * 4;        // 64-j tile index
        const u64 M0 = mrow0[kk];
        const u64 M1 = mrow1[kk];
        const bf16_t* gbb = gb0 + (size_t)kk * 4096;
        const int jb = kk * 64;

#pragma unroll
        for (int kt = 0; kt < 2; ++kt) {
            const int jk = jb + kt * 32;
            const float4 e1a = *reinterpret_cast<const float4*>(E1p + jk);
            const float4 e1b = *reinterpret_cast<const float4*>(E1p + jk + 4);
            const float4 e2a = *reinterpret_cast<const float4*>(E2p + jk);
            const float4 e2b = *reinterpret_cast<const float4*>(E2p + jk + 4);

            const unsigned int b0 = ((unsigned int)(M0 >> (kt * 32)) >> (quad * 8)) & 0xffu;
            const unsigned int b1 = ((unsigned int)(M1 >> (kt * 32)) >> (quad * 8)) & 0xffu;

            const bf16x8 g0 = *reinterpret_cast<const bf16x8*>(gbb + kt * 2048);
            const bf16x8 g1 = *reinterpret_cast<const bf16x8*>(gbb + kt * 2048 + 512);
            const bf16x8 g2 = *reinterpret_cast<const bf16x8*>(gbb + kt * 2048 + 1024);
            const bf16x8 g3 = *reinterpret_cast<const bf16x8*>(gbb + kt * 2048 + 1536);

            const float pe1[8] = {e1a.x, e1a.y, e1a.z, e1a.w, e1b.x, e1b.y, e1b.z, e1b.w};
            const float pe2[8] = {e2a.x, e2a.y, e2a.z, e2a.w, e2b.x, e2b.y, e2b.z, e2b.w};

            bf16x8 af0, af1;
#pragma unroll
            for (int q = 0; q < 8; ++q) {
                const float p0 = (pe1[q] > Ti0) ? E1i0 * pe1[q] : E2i0 * pe2[q];
                const float p1 = (pe1[q] > Ti1) ? E1i1 * pe1[q] : E2i1 * pe2[q];
                af0[q] = ((b0 >> q) & 1u) ? (bf16_t)p0 : (bf16_t)0.f;
                af1[q] = ((b1 >> q) & 1u) ? (bf16_t)p1 : (bf16_t)0.f;
            }

            ad0 = __builtin_amdgcn_mfma_f32_16x16x32_bf16(af0, ones, ad0, 0, 0, 0);
            a00 = __builtin_amdgcn_mfma_f32_16x16x32_bf16(af0, g0, a00, 0, 0, 0);
            a01 = __builtin_amdgcn_mfma_f32_16x16x32_bf16(af0, g1, a01, 0, 0, 0);
            a02 = __builtin_amdgcn_mfma_f32_16x16x32_bf16(af0, g2, a02, 0, 0, 0);
            a03 = __builtin_amdgcn_mfma_f32_16x16x32_bf16(af0, g3, a03, 0, 0, 0);
            ad1 = __builtin_amdgcn_mfma_f32_16x16x32_bf16(af1, ones, ad1, 0, 0, 0);
            a10 = __builtin_amdgcn_mfma_f32_16x16x32_bf16(af1, g0, a10, 0, 0, 0);
            a11 = __builtin_amdgcn_mfma_f32_16x16x32_bf16(af1, g1, a11, 0, 0, 0);
            a12 = __builtin_amdgcn_mfma_f32_16x16x32_bf16(af1, g2, a12, 0, 0, 0);
            a13 = __builtin_amdgcn_mfma_f32_16x16x32_bf16(af1, g3, a13, 0, 0, 0);
        }
    }

    // combine js=1..3 partials into js=0 via LDS (3 rounds, 40 KB)
    floatx4* mine[10] = {&a00, &a01, &a02, &a03, &ad0, &a10, &a11, &a12, &a13, &ad1};
    for (int s = 1; s < 4; ++s) {
        if (js == s) {
#pragma unroll
            for (int c = 0; c < 10; ++c) {
                const floatx4 v = *mine[c];
#pragma unroll
                for (int r = 0; r < 4; ++r)
                    lbuf[((hh * 10 + c) * 4 + r) * 64 + lane] = v[r];
            }
        }
        __syncthreads();
        if (js == 0) {
#pragma unroll
            for (int c = 0; c < 10; ++c) {
#pragma unroll
                for (int r = 0; r < 4; ++r)
                    (*mine[c])[r] += lbuf[((hh * 10 + c) * 4 + r) * 64 + lane];
            }
        }
        __syncthreads();
    }

    if (js == 0) {
        // C/D layout: row = quad*4 + r, col = m
        float* nrow = num + (size_t)jc * ((size_t)N_NODES * F_OUT);
#pragma unroll
        for (int rr = 0; rr < 4; ++rr) {
            const int ib0 = i0 + quad * 4 + rr;
            const int ib1 = ib0 + 16;
            float* d0 = nrow + (size_t)ib0 * F_OUT + hh * D_HID + m;
            float* d1 = nrow + (size_t)ib1 * F_OUT + hh * D_HID + m;
            d0[0] = a00[rr]; d0[16] = a01[rr]; d0[32] = a02[rr]; d0[48] = a03[rr];
            d1[0] = a10[rr]; d1[16] = a11[rr]; d1[32] = a12[rr]; d1[48] = a13[rr];
            if (m == 0) {
                den_g[((size_t)jc * N_NODES + ib0) * NUM_HEADS + hh] = ad0[rr];
                den_g[((size_t)jc * N_NODES + ib1) * NUM_HEADS + hh] = ad1[rr];
            }
        }
    }
}

// ---------------------------------------------------------------------------
// Kernel 3: sum the 2 j-chunk partials, divide, store f32.
// ---------------------------------------------------------------------------
__global__ __launch_bounds__(256) void reduce_kernel(
    const float* __restrict__ num, const float* __restrict__ den,
    float* __restrict__ out)
{
    const int idx = blockIdx.x * 256 + threadIdx.x;
    const int i  = idx >> 8;
    const int c  = idx & 255;
    const int hh = c >> 6;
    const float n = num[idx] + num[(size_t)N_NODES * F_OUT + idx];
    const float d = den[(size_t)i * NUM_HEADS + hh]
                  + den[((size_t)N_NODES + i) * NUM_HEADS + hh];
    out[idx] = n / d;
}

// ---------------------------------------------------------------------------
extern "C" void kernel_launch(void* const* d_in, const int* in_sizes, int n_in,
                              void* d_out, int out_size, void* d_ws, size_t ws_size,
                              hipStream_t stream)
{
    const float* hmat = (const float*)d_in[0];   // (4096, 128) f32
    const float* adj  = (const float*)d_in[1];   // (4096, 4096) f32
    const float* Wp   = (const float*)d_in[2];   // (128, 256) f32
    const float* Wa   = (const float*)d_in[3];   // (128, 128) f32
    const float* watt = (const float*)d_in[4];   // (64,) f32
    float* out = (float*)d_out;                  // (4096, 256) f32

    char* ws = (char*)d_ws;
    bf16_t* GB  = (bf16_t*)ws;                                   // 2 MiB
    float*  el  = (float*)(ws + (2ull << 20));                   // 64 KiB
    float*  E1r = (float*)(ws + (2ull << 20) + (64ull << 10));   // 64 KiB
    float*  E2r = (float*)(ws + (2ull << 20) + (128ull << 10));  // 64 KiB
    u64*    msk = (u64*)  (ws + (2ull << 20) + (192ull << 10));  // 2 MiB
    const size_t baseoff = (4ull << 20) + (192ull << 10);

    float* num = (float*)(ws + baseoff);                         // 2 x 4 MiB
    float* den = (float*)(ws + baseoff + 2ull * N_NODES * F_OUT * 4);  // 2 x 64 KiB

    mask_kernel<<<1024, 256, 0, stream>>>(adj, msk);
    proj_kernel<<<1024, 384, 0, stream>>>(hmat, Wp, Wa, watt, GB, el, E1r, E2r);
    attn_kernel<<<dim3(128, 2), 1024, 0, stream>>>(msk, GB, el, E1r, E2r, num, den);
    reduce_kernel<<<(N_NODES * F_OUT) / 256, 256, 0, stream>>>(num, den, out);
}